// Round 11
// baseline (528.519 us; speedup 1.0000x reference)
//
#include <hip/hip_runtime.h>
#include <hip/hip_bf16.h>
#include <hip/hip_fp16.h>
#include <math.h>

#define NF 256    // input features
#define NO 64     // heads*c1 = 8*8
#define NHEAD 8
#define NEG_SLOPE 0.2f
#define BM 64     // gemm row tile
#define KB 64     // gemm k tile
#define BKT 128   // nodes per dst-bucket (d>>7); d_local = 7 bits
#define NBLK 256  // edge-chunk blocks for binning
#define RCAP 8192 // LDS record capacity in k_csr

__device__ __forceinline__ float lrelu(float x) { return x > 0.f ? x : NEG_SLOPE * x; }

typedef _Float16 f16x2 __attribute__((ext_vector_type(2)));

__device__ __forceinline__ unsigned f2u(float a, float b) {
    return __builtin_bit_cast(unsigned, __float22half2_rn(make_float2(a, b)));
}
__device__ __forceinline__ float dot2f(unsigned a, unsigned b, float c) {
#if __has_builtin(__builtin_amdgcn_fdot2)
    return __builtin_amdgcn_fdot2(__builtin_bit_cast(f16x2, a),
                                  __builtin_bit_cast(f16x2, b), c, false);
#else
    float2 fa = __half22float2(__builtin_bit_cast(__half2, a));
    float2 fb = __half22float2(__builtin_bit_cast(__half2, b));
    return fmaf(fa.x, fb.x, fmaf(fa.y, fb.y, c));
#endif
}

// ---------------------------------------------------------------------------
// K1 (fused): blocks [0,GB) = tiled GEMM h1=x@W1 via v_dot2_f32_f16.
// fp16 LDS tiles (x: [64][36] uint k-pairs, W: [32][68] uint k-pair-interleaved)
// = 19.5KB -> 8 blocks/CU; LDS-read traffic and VALU ops both halved vs f32.
// Staging is round-8 style: global->convert->LDS in-loop, NO registers held
// across barriers (round-9's cross-barrier prefetch caused the VGPR-256 spill;
// its fp16 numerics PASSED, so dtype is proven safe).
// blocks [GB,GB+NBLK) = per-chunk bucket histogram -> M[b][blk].
// ---------------------------------------------------------------------------
__global__ __launch_bounds__(256) void k_front(
    const float* __restrict__ x, const float* __restrict__ W,
    const float* __restrict__ a_src, const float* __restrict__ a_dst,
    __half* __restrict__ h1h, float* __restrict__ as1, float* __restrict__ ad1,
    const int* __restrict__ eidx, unsigned* __restrict__ M,
    float* __restrict__ gacc, int N, int E, int GB, int NB, int CH)
{
    __shared__ unsigned xl2[BM][36];      // [row][k-pair], pad to 36 (16B-aligned rows)
    __shared__ unsigned wl2[KB / 2][68];  // [k-pair][col] = fp16x2(W[2p][c],W[2p+1][c])
    __shared__ unsigned hist[512];

    if (blockIdx.x >= GB) {
        // ---- histogram path ----
        for (int i = threadIdx.x; i < NB; i += 256) hist[i] = 0;
        __syncthreads();
        const int blk = blockIdx.x - GB;
        const int lo = blk * CH;
        const int hi = min(lo + CH, E + N);
        for (int i = lo + (int)threadIdx.x; i < hi; i += 256) {
            int d = (i < E) ? eidx[E + i] : (i - E);
            atomicAdd(&hist[d >> 7], 1u);
        }
        __syncthreads();
        for (int b = threadIdx.x; b < NB; b += 256)
            M[(size_t)b * NBLK + blk] = hist[b];
        return;
    }

    // ---- GEMM path ----
    if (blockIdx.x == 0) {
        for (int i = threadIdx.x; i < 1024; i += 256) gacc[i] = 0.f;  // 64 x 16
    }
    const int t  = threadIdx.x;
    const int tx = t & 15;        // col group / k-col group
    const int ty = t >> 4;        // row group
    const int row0 = blockIdx.x * BM;

    float acc[4][4] = {};

    for (int kc = 0; kc < NF; kc += KB) {
        // stage x tile: thread loads rows ty+16i, k-cols kc+4tx..+3 (coalesced),
        // converts to 2 fp16-pairs, stores uint2. No regs live across barriers.
        #pragma unroll
        for (int i = 0; i < 4; ++i) {
            int r = ty + 16 * i;
            int row = row0 + r; if (row >= N) row = N - 1;
            float4 v = *(const float4*)(x + (size_t)row * NF + kc + 4 * tx);
            *(uint2*)&xl2[r][2 * tx] = make_uint2(f2u(v.x, v.y), f2u(v.z, v.w));
        }
        // stage W tile: thread handles k-pairs p = ty+16i, cols 4tx..+3;
        // loads W rows 2p,2p+1 and interleaves into fp16x2 per column.
        #pragma unroll
        for (int i = 0; i < 2; ++i) {
            int p = ty + 16 * i;
            float4 lo = *(const float4*)(W + (size_t)(kc + 2 * p) * NO + 4 * tx);
            float4 hi = *(const float4*)(W + (size_t)(kc + 2 * p + 1) * NO + 4 * tx);
            *(uint4*)&wl2[p][4 * tx] =
                make_uint4(f2u(lo.x, hi.x), f2u(lo.y, hi.y),
                           f2u(lo.z, hi.z), f2u(lo.w, hi.w));
        }
        __syncthreads();

        // compute: 8 chunks x (8 ds_read_b128 + 64 dot2)  [half the f32 cost]
        #pragma unroll
        for (int kk = 0; kk < KB / 2; kk += 4) {
            uint4 xv[4], wv[4];
            #pragma unroll
            for (int r = 0; r < 4; ++r)
                xv[r] = *(const uint4*)&xl2[4 * ty + r][kk];   // 4 k-pairs of row
            #pragma unroll
            for (int j = 0; j < 4; ++j)
                wv[j] = *(const uint4*)&wl2[kk + j][4 * tx];   // 4 cols of k-pair
            #pragma unroll
            for (int r = 0; r < 4; ++r) {
                #pragma unroll
                for (int j = 0; j < 4; ++j) {
                    unsigned xa = (j == 0) ? xv[r].x : (j == 1) ? xv[r].y
                                : (j == 2) ? xv[r].z : xv[r].w;
                    acc[r][0] = dot2f(xa, wv[j].x, acc[r][0]);
                    acc[r][1] = dot2f(xa, wv[j].y, acc[r][1]);
                    acc[r][2] = dot2f(xa, wv[j].z, acc[r][2]);
                    acc[r][3] = dot2f(xa, wv[j].w, acc[r][3]);
                }
            }
        }
        __syncthreads();
    }

    const float4 avs = *(const float4*)(a_src + 4 * tx);
    const float4 avd = *(const float4*)(a_dst + 4 * tx);
    #pragma unroll
    for (int r = 0; r < 4; ++r) {
        int row = row0 + 4 * ty + r;
        if (row >= N) continue;
        float4 o = make_float4(acc[r][0], acc[r][1], acc[r][2], acc[r][3]);
        __half2 p0 = __float22half2_rn(make_float2(o.x, o.y));
        __half2 p1 = __float22half2_rn(make_float2(o.z, o.w));
        __half2* dst2 = (__half2*)(h1h + (size_t)row * NO + 4 * tx);
        dst2[0] = p0;
        dst2[1] = p1;
        float vs = o.x * avs.x + o.y * avs.y + o.z * avs.z + o.w * avs.w;
        float vd = o.x * avd.x + o.y * avd.y + o.z * avd.z + o.w * avd.w;
        vs += __shfl_xor(vs, 1);
        vd += __shfl_xor(vd, 1);
        if ((tx & 1) == 0) {
            as1[row * NHEAD + (tx >> 1)] = vs;
            ad1[row * NHEAD + (tx >> 1)] = vd;
        }
    }
}

// ---------------------------------------------------------------------------
// K2: single block, 1024 threads. Row-sum M -> totals; serial scan -> Bbase;
// per-row uint4 wave scans -> in-place scatter cursors in M.
// ---------------------------------------------------------------------------
__global__ __launch_bounds__(1024) void k_scan2(
    unsigned* __restrict__ M, unsigned* __restrict__ Bbase, int NB)
{
    __shared__ unsigned tot[512];
    __shared__ unsigned basel[513];
    const int t = threadIdx.x, lane = t & 63, w = t >> 6;  // 16 waves

    for (int b = w; b < NB; b += 16) {
        uint4 v = ((const uint4*)&M[(size_t)b * NBLK])[lane];
        unsigned s = v.x + v.y + v.z + v.w;
        #pragma unroll
        for (int m = 1; m < 64; m <<= 1) s += __shfl_xor(s, m);
        if (lane == 0) tot[b] = s;
    }
    __syncthreads();
    if (t == 0) {
        unsigned r = 0;
        for (int b = 0; b < NB; ++b) { basel[b] = r; r += tot[b]; }
        basel[NB] = r;
    }
    __syncthreads();
    for (int b = t; b <= NB; b += 1024) Bbase[b] = basel[b];
    for (int b = w; b < NB; b += 16) {
        uint4 v = ((const uint4*)&M[(size_t)b * NBLK])[lane];
        unsigned lsum = v.x + v.y + v.z + v.w;
        unsigned p = lsum;
        #pragma unroll
        for (int d = 1; d < 64; d <<= 1) {
            unsigned q = __shfl_up(p, d);
            if (lane >= d) p += q;
        }
        unsigned c0 = basel[b] + p - lsum;
        uint4 o;
        o.x = c0;
        o.y = c0 + v.x;
        o.z = o.y + v.y;
        o.w = o.z + v.z;
        ((uint4*)&M[(size_t)b * NBLK])[lane] = o;
    }
}

// ---------------------------------------------------------------------------
// K3: scatter packed records (s<<7 | d_local) into bucket-contiguous regions.
// ---------------------------------------------------------------------------
__global__ __launch_bounds__(256) void k_bscatter(
    const int* __restrict__ eidx, int E, int N, int NB, int CH,
    const unsigned* __restrict__ M, unsigned* __restrict__ rbuf)
{
    __shared__ unsigned cur[512];
    const int blk = blockIdx.x;
    for (int b = threadIdx.x; b < NB; b += 256)
        cur[b] = M[(size_t)b * NBLK + blk];
    __syncthreads();
    const int lo = blk * CH;
    const int hi = min(lo + CH, E + N);
    for (int i = lo + (int)threadIdx.x; i < hi; i += 256) {
        int s, d;
        if (i < E) { s = eidx[i]; d = eidx[E + i]; }
        else       { s = i - E;   d = i - E; }
        unsigned pos = atomicAdd(&cur[d >> 7], 1u);
        rbuf[pos] = ((unsigned)s << 7) | (unsigned)(d & (BKT - 1));
    }
}

// ---------------------------------------------------------------------------
// K4: per-bucket LDS counting sort -> node-ordered csr (in place) + offs.
// ---------------------------------------------------------------------------
__global__ __launch_bounds__(256) void k_csr(
    const unsigned* __restrict__ Bbase, int N, int NB,
    unsigned* __restrict__ rbuf, unsigned* __restrict__ offs)
{
    __shared__ unsigned recs[RCAP];
    __shared__ unsigned nhist[BKT];
    __shared__ unsigned ncur[BKT];
    __shared__ unsigned wtotS;
    const int b = blockIdx.x;
    const unsigned base = Bbase[b], end = Bbase[b + 1];
    const int cnt = (int)(end - base);
    const int nodes = min(BKT, N - b * BKT);

    for (int i = threadIdx.x; i < BKT; i += 256) nhist[i] = 0;
    __syncthreads();
    for (int i = threadIdx.x; i < cnt; i += 256) {
        unsigned r = rbuf[base + i];
        recs[i] = r;
        atomicAdd(&nhist[r & (BKT - 1)], 1u);
    }
    __syncthreads();
    const int tl = threadIdx.x & 127;
    unsigned v = nhist[tl], p = v;
    #pragma unroll
    for (int d = 1; d < 64; d <<= 1) {
        unsigned q = __shfl_up(p, d);
        if ((tl & 63) >= d) p += q;
    }
    if (threadIdx.x == 63) wtotS = p;
    __syncthreads();
    unsigned excl = base + ((tl >= 64) ? wtotS : 0u) + p - v;
    if (threadIdx.x < 128) {
        ncur[tl] = excl;
        if (tl < nodes) offs[b * BKT + tl] = excl;
    }
    if (b == NB - 1 && threadIdx.x == 0) offs[N] = end;
    __syncthreads();
    for (int i = threadIdx.x; i < cnt; i += 256) {
        unsigned r = recs[i];
        unsigned pos = atomicAdd(&ncur[r & (BKT - 1)], 1u);
        rbuf[pos] = r >> 7;
    }
}

// ---------------------------------------------------------------------------
// K5: layer-1 GAT aggregation. One wave per dst node, 8 lanes/edge
// (slot = lane>>3, head = lane&7), exp/lrelu once per (edge,head),
// 4 edges in flight per lane. Fused epilogue: relu(acc/den+b1) . W2 -> h2.
// ---------------------------------------------------------------------------
__global__ __launch_bounds__(256) void k_gat1(
    const unsigned* __restrict__ offs, const int* __restrict__ csr,
    const float4* __restrict__ h1q,
    const float* __restrict__ as1, const float* __restrict__ ad1,
    const float* __restrict__ b1, const float* __restrict__ W2,
    float* __restrict__ h2, int N)
{
    const int lane = threadIdx.x & 63;
    const int n = blockIdx.x * (blockDim.x >> 6) + (threadIdx.x >> 6);
    if (n >= N) return;
    const int slot = lane >> 3;
    const int head = lane & 7;
    const unsigned s0 = offs[n];
    const unsigned deg = offs[n + 1] - s0;
    const float ad = ad1[n * NHEAD + head];

    float acc[8] = {};
    float den = 0.f;

    unsigned k = (unsigned)slot;
    for (; k + 24 < deg; k += 32) {
        int sA = csr[s0 + k],      sB = csr[s0 + k + 8];
        int sC = csr[s0 + k + 16], sD = csr[s0 + k + 24];
        float aA = as1[sA * NHEAD + head], aB = as1[sB * NHEAD + head];
        float aC = as1[sC * NHEAD + head], aD = as1[sD * NHEAD + head];
        float4 rA = h1q[(unsigned)sA * 8u + head];
        float4 rB = h1q[(unsigned)sB * 8u + head];
        float4 rC = h1q[(unsigned)sC * 8u + head];
        float4 rD = h1q[(unsigned)sD * 8u + head];
        float pA = __expf(lrelu(aA + ad));
        float pB = __expf(lrelu(aB + ad));
        float pC = __expf(lrelu(aC + ad));
        float pD = __expf(lrelu(aD + ad));
        den += (pA + pB) + (pC + pD);
        const __half2* hA = (const __half2*)&rA;
        const __half2* hB = (const __half2*)&rB;
        const __half2* hC = (const __half2*)&rC;
        const __half2* hD = (const __half2*)&rD;
        #pragma unroll
        for (int j = 0; j < 4; ++j) {
            float2 fA = __half22float2(hA[j]);
            float2 fB = __half22float2(hB[j]);
            float2 fC = __half22float2(hC[j]);
            float2 fD = __half22float2(hD[j]);
            acc[2 * j]     = fmaf(pA, fA.x, acc[2 * j]);
            acc[2 * j + 1] = fmaf(pA, fA.y, acc[2 * j + 1]);
            acc[2 * j]     = fmaf(pB, fB.x, acc[2 * j]);
            acc[2 * j + 1] = fmaf(pB, fB.y, acc[2 * j + 1]);
            acc[2 * j]     = fmaf(pC, fC.x, acc[2 * j]);
            acc[2 * j + 1] = fmaf(pC, fC.y, acc[2 * j + 1]);
            acc[2 * j]     = fmaf(pD, fD.x, acc[2 * j]);
            acc[2 * j + 1] = fmaf(pD, fD.y, acc[2 * j + 1]);
        }
    }
    for (; k + 8 < deg; k += 16) {
        int sA = csr[s0 + k], sB = csr[s0 + k + 8];
        float aA = as1[sA * NHEAD + head], aB = as1[sB * NHEAD + head];
        float4 rA = h1q[(unsigned)sA * 8u + head];
        float4 rB = h1q[(unsigned)sB * 8u + head];
        float pA = __expf(lrelu(aA + ad));
        float pB = __expf(lrelu(aB + ad));
        den += pA + pB;
        const __half2* hA = (const __half2*)&rA;
        const __half2* hB = (const __half2*)&rB;
        #pragma unroll
        for (int j = 0; j < 4; ++j) {
            float2 fA = __half22float2(hA[j]);
            float2 fB = __half22float2(hB[j]);
            acc[2 * j]     = fmaf(pA, fA.x, acc[2 * j]);
            acc[2 * j + 1] = fmaf(pA, fA.y, acc[2 * j + 1]);
            acc[2 * j]     = fmaf(pB, fB.x, acc[2 * j]);
            acc[2 * j + 1] = fmaf(pB, fB.y, acc[2 * j + 1]);
        }
    }
    if (k < deg) {
        int s = csr[s0 + k];
        float a = as1[s * NHEAD + head];
        float4 r = h1q[(unsigned)s * 8u + head];
        float p = __expf(lrelu(a + ad));
        den += p;
        const __half2* hh = (const __half2*)&r;
        #pragma unroll
        for (int j = 0; j < 4; ++j) {
            float2 f = __half22float2(hh[j]);
            acc[2 * j]     = fmaf(p, f.x, acc[2 * j]);
            acc[2 * j + 1] = fmaf(p, f.y, acc[2 * j + 1]);
        }
    }

    #pragma unroll
    for (int r = 0; r < 8; ++r) {
        acc[r] += __shfl_xor(acc[r], 8);
        acc[r] += __shfl_xor(acc[r], 16);
        acc[r] += __shfl_xor(acc[r], 32);
    }
    den += __shfl_xor(den, 8);
    den += __shfl_xor(den, 16);
    den += __shfl_xor(den, 32);

    const float4 b0 = ((const float4*)b1)[head * 2];
    const float4 b1v = ((const float4*)b1)[head * 2 + 1];
    const float4 w0 = ((const float4*)W2)[head * 2];
    const float4 w1v = ((const float4*)W2)[head * 2 + 1];
    const float inv = 1.f / den;
    float tt = 0.f;
    tt += fmaxf(fmaf(acc[0], inv, b0.x), 0.f) * w0.x;
    tt += fmaxf(fmaf(acc[1], inv, b0.y), 0.f) * w0.y;
    tt += fmaxf(fmaf(acc[2], inv, b0.z), 0.f) * w0.z;
    tt += fmaxf(fmaf(acc[3], inv, b0.w), 0.f) * w0.w;
    tt += fmaxf(fmaf(acc[4], inv, b1v.x), 0.f) * w1v.x;
    tt += fmaxf(fmaf(acc[5], inv, b1v.y), 0.f) * w1v.y;
    tt += fmaxf(fmaf(acc[6], inv, b1v.z), 0.f) * w1v.z;
    tt += fmaxf(fmaf(acc[7], inv, b1v.w), 0.f) * w1v.w;
    tt += __shfl_xor(tt, 1);
    tt += __shfl_xor(tt, 2);
    tt += __shfl_xor(tt, 4);
    if (lane == 0) h2[n] = tt;
}

// ---------------------------------------------------------------------------
// K6 (fused): layer-2 GAT + mean-pool accumulate, 64 nodes/block,
// wave-0 segmented reduce, padded gacc atomics.
// ---------------------------------------------------------------------------
__global__ __launch_bounds__(1024) void k_gat2pool(
    const unsigned* __restrict__ offs, const int* __restrict__ csr,
    const float* __restrict__ h2, const int* __restrict__ batch,
    const float* __restrict__ a_src2, const float* __restrict__ a_dst2,
    const float* __restrict__ b2, float* __restrict__ gacc, int N)
{
    __shared__ float vals[64];
    __shared__ int gid[64];
    const int t = threadIdx.x;
    if (t < 64) gid[t] = -1;
    __syncthreads();

    const int lane = t & 63;
    const int ql = lane & 15;
    const int slot = (t >> 6) * 4 + (lane >> 4);
    const int n = blockIdx.x * 64 + slot;

    if (n < N) {
        const float aS = a_src2[0], aD = a_dst2[0];
        const unsigned s0 = offs[n], s1 = offs[n + 1];
        const float ad = h2[n] * aD;
        float num = 0.f, den = 0.f;
        for (unsigned j = s0 + (unsigned)ql; j < s1; j += 16) {
            float hs = h2[csr[j]];
            float p = __expf(lrelu(hs * aS + ad));
            num = fmaf(p, hs, num);
            den += p;
        }
        #pragma unroll
        for (int msk = 1; msk < 16; msk <<= 1) {
            num += __shfl_xor(num, msk);
            den += __shfl_xor(den, msk);
        }
        if (ql == 0) {
            vals[slot] = num / den + b2[0];
            gid[slot] = batch[n];
        }
    }
    __syncthreads();

    if (t < 64) {
        int g = gid[t];
        float o = (g >= 0) ? vals[t] : 0.f;
        const int g0 = __shfl(g, 0);
        const bool same = (g == g0);
        float s = same ? o : 0.f;
        float c = (same && g >= 0) ? 1.f : 0.f;
        #pragma unroll
        for (int msk = 1; msk < 64; msk <<= 1) {
            s += __shfl_xor(s, msk);
            c += __shfl_xor(c, msk);
        }
        if (t == 0) {
            unsafeAtomicAdd(&gacc[g0 * 16], s);
            unsafeAtomicAdd(&gacc[g0 * 16 + 1], c);
        }
        if (g >= 0 && !same) {
            unsafeAtomicAdd(&gacc[g * 16], o);
            unsafeAtomicAdd(&gacc[g * 16 + 1], 1.0f);
        }
    }
}

// ---------------------------------------------------------------------------
// K7: final per-graph mean
// ---------------------------------------------------------------------------
__global__ void k_final(const float* __restrict__ gacc,
                        float* __restrict__ out, int G)
{
    int g = blockIdx.x * blockDim.x + threadIdx.x;
    if (g < G) out[g] = gacc[g * 16] / fmaxf(gacc[g * 16 + 1], 1.0f);
}

// ---------------------------------------------------------------------------
extern "C" void kernel_launch(void* const* d_in, const int* in_sizes, int n_in,
                              void* d_out, int out_size, void* d_ws, size_t ws_size,
                              hipStream_t stream)
{
    const float* x      = (const float*)d_in[0];
    const int*   eidx   = (const int*)d_in[1];
    const int*   batch  = (const int*)d_in[2];
    const float* W1     = (const float*)d_in[3];
    const float* a_src1 = (const float*)d_in[4];
    const float* a_dst1 = (const float*)d_in[5];
    const float* b1     = (const float*)d_in[6];
    const float* W2     = (const float*)d_in[7];
    const float* a_src2 = (const float*)d_in[8];
    const float* a_dst2 = (const float*)d_in[9];
    const float* b2     = (const float*)d_in[10];

    const int N = in_sizes[0] / NF;      // 50000
    const int E = in_sizes[1] / 2;       // 1600000
    const int G = out_size;              // 64
    const int ETOT = E + N;
    const int NB = (N + BKT - 1) / BKT;  // 391 buckets
    const int CH = (ETOT + NBLK - 1) / NBLK;
    const int GB = (N + BM - 1) / BM;    // 782 gemm blocks

    // workspace layout (bytes)
    char* w = (char*)d_ws;
    __half*   h1h   = (__half*)(w + 0);           //  6,400,000 (fp16)
    float*    as1   = (float*)(w + 6400000);      //  1,600,000
    float*    ad1   = (float*)(w + 8000000);      //  1,600,000
    float*    h2    = (float*)(w + 9600000);      //    200,000
    unsigned* offs  = (unsigned*)(w + 9800000);   //    200,064
    unsigned* rbuf  = (unsigned*)(w + 10000064);  //  6,600,000 (records -> csr)
    unsigned* M     = (unsigned*)(w + 16600064);  //    400,384 (NB*NBLK)
    unsigned* Bbase = (unsigned*)(w + 17000448);  //      2,048
    float*    gacc  = (float*)(w + 17002496);     //      4,096 (64 graphs x 16)

    k_front<<<GB + NBLK, 256, 0, stream>>>(x, W1, a_src1, a_dst1,
                                           h1h, as1, ad1,
                                           eidx, M, gacc, N, E, GB, NB, CH);
    k_scan2<<<1, 1024, 0, stream>>>(M, Bbase, NB);
    k_bscatter<<<NBLK, 256, 0, stream>>>(eidx, E, N, NB, CH, M, rbuf);
    k_csr<<<NB, 256, 0, stream>>>(Bbase, N, NB, rbuf, offs);

    const int* csr = (const int*)rbuf;
    k_gat1<<<(N + 3) / 4, 256, 0, stream>>>(offs, csr, (const float4*)h1h,
                                            as1, ad1, b1, W2, h2, N);
    k_gat2pool<<<(N + 63) / 64, 1024, 0, stream>>>(offs, csr, h2, batch,
                                                   a_src2, a_dst2, b2, gacc, N);
    k_final<<<1, 64, 0, stream>>>(gacc, (float*)d_out, G);
}

// Round 12
// 144.710 us; speedup vs baseline: 3.6523x; 3.6523x over previous
//
#include <hip/hip_runtime.h>
#include <hip/hip_bf16.h>
#include <hip/hip_fp16.h>
#include <math.h>

#define NF 256    // input features
#define NO 64     // heads*c1 = 8*8
#define NHEAD 8
#define NEG_SLOPE 0.2f
#define BM 128    // gemm row tile (8 rows/thread x 16 row-groups)
#define KB 64     // gemm k tile
#define LS 68     // gemm LDS row stride (floats)
#define BKT 128   // nodes per dst-bucket (d>>7); d_local = 7 bits
#define NBLK 256  // edge-chunk blocks for binning
#define RCAP 8192 // LDS record capacity in k_csr

__device__ __forceinline__ float lrelu(float x) { return x > 0.f ? x : NEG_SLOPE * x; }

// ---------------------------------------------------------------------------
// K1 (fused): blocks [0,GB) = tiled f32 GEMM h1=x@W1 (+fused alphas, fp16
// store); blocks [GB,GB+NBLK) = per-chunk bucket histogram -> M[b][blk].
// GEMM: 128x64 block, 8x4 register tile per thread (two 4-row sub-tiles
// sharing each wv load) -> FMA/LDS-read 10.7 vs 8 for the old 4x4.
// f32 fmaf ONLY: both fp16-dot2 variants (r9 prefetch, r11 in-loop) spilled
// to VGPR 256 + ~0.5GB scratch — the fdot2/bit_cast codegen is the cause.
// ---------------------------------------------------------------------------
__global__ __launch_bounds__(256) void k_front(
    const float* __restrict__ x, const float* __restrict__ W,
    const float* __restrict__ a_src, const float* __restrict__ a_dst,
    __half* __restrict__ h1h, float* __restrict__ as1, float* __restrict__ ad1,
    const int* __restrict__ eidx, unsigned* __restrict__ M,
    float* __restrict__ gacc, int N, int E, int GB, int NB, int CH)
{
    __shared__ float xl[BM][LS];   // 34816 B
    __shared__ float wl[KB][LS];   // 17408 B  (total 52224 -> 3 blocks/CU)

    if (blockIdx.x >= GB) {
        // ---- histogram path (hist aliases xl) ----
        unsigned* hist = (unsigned*)&xl[0][0];
        for (int i = threadIdx.x; i < NB; i += 256) hist[i] = 0;
        __syncthreads();
        const int blk = blockIdx.x - GB;
        const int lo = blk * CH;
        const int hi = min(lo + CH, E + N);
        for (int i = lo + (int)threadIdx.x; i < hi; i += 256) {
            int d = (i < E) ? eidx[E + i] : (i - E);
            atomicAdd(&hist[d >> 7], 1u);
        }
        __syncthreads();
        for (int b = threadIdx.x; b < NB; b += 256)
            M[(size_t)b * NBLK + blk] = hist[b];
        return;
    }

    // ---- GEMM path ----
    if (blockIdx.x == 0) {
        for (int i = threadIdx.x; i < 1024; i += 256) gacc[i] = 0.f;  // 64 x 16
    }
    const int t  = threadIdx.x;
    const int tx = t & 15;        // col group: cols 4tx..4tx+3
    const int ty = t >> 4;        // row group: rows 8ty..8ty+7
    const int row0 = blockIdx.x * BM;

    float acc[8][4] = {};

    for (int kc = 0; kc < NF; kc += KB) {
        // stage x tile: 128 rows x 64 k, thread loads rows ty+16i (i=0..7)
        #pragma unroll
        for (int i = 0; i < 8; ++i) {
            int r = ty + 16 * i;
            int row = row0 + r; if (row >= N) row = N - 1;
            float4 v = *(const float4*)(x + (size_t)row * NF + kc + 4 * tx);
            *(float4*)&xl[r][4 * tx] = v;
        }
        // stage W tile: 64 k x 64 cols, thread loads k = ty+16i (i=0..3)
        #pragma unroll
        for (int i = 0; i < 4; ++i) {
            int k = ty + 16 * i;
            float4 v = *(const float4*)(W + (size_t)(kc + k) * NO + 4 * tx);
            *(float4*)&wl[k][4 * tx] = v;
        }
        __syncthreads();

        #pragma unroll
        for (int k = 0; k < KB; k += 4) {
            float4 wv[4];
            #pragma unroll
            for (int kk = 0; kk < 4; ++kk)
                wv[kk] = *(const float4*)&wl[k + kk][4 * tx];
            // sub-tile A: rows 8ty..8ty+3
            {
                float4 xv[4];
                #pragma unroll
                for (int r = 0; r < 4; ++r)
                    xv[r] = *(const float4*)&xl[8 * ty + r][k];
                #pragma unroll
                for (int r = 0; r < 4; ++r) {
                    float4 xr = xv[r];
                    #pragma unroll
                    for (int kk = 0; kk < 4; ++kk) {
                        float xk = (kk == 0) ? xr.x : (kk == 1) ? xr.y
                                 : (kk == 2) ? xr.z : xr.w;
                        acc[r][0] = fmaf(xk, wv[kk].x, acc[r][0]);
                        acc[r][1] = fmaf(xk, wv[kk].y, acc[r][1]);
                        acc[r][2] = fmaf(xk, wv[kk].z, acc[r][2]);
                        acc[r][3] = fmaf(xk, wv[kk].w, acc[r][3]);
                    }
                }
            }
            // sub-tile B: rows 8ty+4..8ty+7 (reuses wv)
            {
                float4 xv[4];
                #pragma unroll
                for (int r = 0; r < 4; ++r)
                    xv[r] = *(const float4*)&xl[8 * ty + 4 + r][k];
                #pragma unroll
                for (int r = 0; r < 4; ++r) {
                    float4 xr = xv[r];
                    #pragma unroll
                    for (int kk = 0; kk < 4; ++kk) {
                        float xk = (kk == 0) ? xr.x : (kk == 1) ? xr.y
                                 : (kk == 2) ? xr.z : xr.w;
                        acc[4 + r][0] = fmaf(xk, wv[kk].x, acc[4 + r][0]);
                        acc[4 + r][1] = fmaf(xk, wv[kk].y, acc[4 + r][1]);
                        acc[4 + r][2] = fmaf(xk, wv[kk].z, acc[4 + r][2]);
                        acc[4 + r][3] = fmaf(xk, wv[kk].w, acc[4 + r][3]);
                    }
                }
            }
        }
        __syncthreads();
    }

    const float4 avs = *(const float4*)(a_src + 4 * tx);
    const float4 avd = *(const float4*)(a_dst + 4 * tx);
    #pragma unroll
    for (int r = 0; r < 8; ++r) {
        int row = row0 + 8 * ty + r;
        if (row >= N) continue;
        float4 o = make_float4(acc[r][0], acc[r][1], acc[r][2], acc[r][3]);
        __half2 p0 = __float22half2_rn(make_float2(o.x, o.y));
        __half2 p1 = __float22half2_rn(make_float2(o.z, o.w));
        __half2* dst2 = (__half2*)(h1h + (size_t)row * NO + 4 * tx);
        dst2[0] = p0;
        dst2[1] = p1;
        float vs = o.x * avs.x + o.y * avs.y + o.z * avs.z + o.w * avs.w;
        float vd = o.x * avd.x + o.y * avd.y + o.z * avd.z + o.w * avd.w;
        vs += __shfl_xor(vs, 1);
        vd += __shfl_xor(vd, 1);
        if ((tx & 1) == 0) {
            as1[row * NHEAD + (tx >> 1)] = vs;
            ad1[row * NHEAD + (tx >> 1)] = vd;
        }
    }
}

// ---------------------------------------------------------------------------
// K2: single block, 1024 threads. Row-sum M -> totals; serial scan -> Bbase;
// per-row uint4 wave scans -> in-place scatter cursors in M.
// ---------------------------------------------------------------------------
__global__ __launch_bounds__(1024) void k_scan2(
    unsigned* __restrict__ M, unsigned* __restrict__ Bbase, int NB)
{
    __shared__ unsigned tot[512];
    __shared__ unsigned basel[513];
    const int t = threadIdx.x, lane = t & 63, w = t >> 6;  // 16 waves

    for (int b = w; b < NB; b += 16) {
        uint4 v = ((const uint4*)&M[(size_t)b * NBLK])[lane];
        unsigned s = v.x + v.y + v.z + v.w;
        #pragma unroll
        for (int m = 1; m < 64; m <<= 1) s += __shfl_xor(s, m);
        if (lane == 0) tot[b] = s;
    }
    __syncthreads();
    if (t == 0) {
        unsigned r = 0;
        for (int b = 0; b < NB; ++b) { basel[b] = r; r += tot[b]; }
        basel[NB] = r;
    }
    __syncthreads();
    for (int b = t; b <= NB; b += 1024) Bbase[b] = basel[b];
    for (int b = w; b < NB; b += 16) {
        uint4 v = ((const uint4*)&M[(size_t)b * NBLK])[lane];
        unsigned lsum = v.x + v.y + v.z + v.w;
        unsigned p = lsum;
        #pragma unroll
        for (int d = 1; d < 64; d <<= 1) {
            unsigned q = __shfl_up(p, d);
            if (lane >= d) p += q;
        }
        unsigned c0 = basel[b] + p - lsum;
        uint4 o;
        o.x = c0;
        o.y = c0 + v.x;
        o.z = o.y + v.y;
        o.w = o.z + v.z;
        ((uint4*)&M[(size_t)b * NBLK])[lane] = o;
    }
}

// ---------------------------------------------------------------------------
// K3: scatter packed records (s<<7 | d_local) into bucket-contiguous regions.
// ---------------------------------------------------------------------------
__global__ __launch_bounds__(256) void k_bscatter(
    const int* __restrict__ eidx, int E, int N, int NB, int CH,
    const unsigned* __restrict__ M, unsigned* __restrict__ rbuf)
{
    __shared__ unsigned cur[512];
    const int blk = blockIdx.x;
    for (int b = threadIdx.x; b < NB; b += 256)
        cur[b] = M[(size_t)b * NBLK + blk];
    __syncthreads();
    const int lo = blk * CH;
    const int hi = min(lo + CH, E + N);
    for (int i = lo + (int)threadIdx.x; i < hi; i += 256) {
        int s, d;
        if (i < E) { s = eidx[i]; d = eidx[E + i]; }
        else       { s = i - E;   d = i - E; }
        unsigned pos = atomicAdd(&cur[d >> 7], 1u);
        rbuf[pos] = ((unsigned)s << 7) | (unsigned)(d & (BKT - 1));
    }
}

// ---------------------------------------------------------------------------
// K4: per-bucket LDS counting sort -> node-ordered csr (in place) + offs.
// ---------------------------------------------------------------------------
__global__ __launch_bounds__(256) void k_csr(
    const unsigned* __restrict__ Bbase, int N, int NB,
    unsigned* __restrict__ rbuf, unsigned* __restrict__ offs)
{
    __shared__ unsigned recs[RCAP];
    __shared__ unsigned nhist[BKT];
    __shared__ unsigned ncur[BKT];
    __shared__ unsigned wtotS;
    const int b = blockIdx.x;
    const unsigned base = Bbase[b], end = Bbase[b + 1];
    const int cnt = (int)(end - base);
    const int nodes = min(BKT, N - b * BKT);

    for (int i = threadIdx.x; i < BKT; i += 256) nhist[i] = 0;
    __syncthreads();
    for (int i = threadIdx.x; i < cnt; i += 256) {
        unsigned r = rbuf[base + i];
        recs[i] = r;
        atomicAdd(&nhist[r & (BKT - 1)], 1u);
    }
    __syncthreads();
    const int tl = threadIdx.x & 127;
    unsigned v = nhist[tl], p = v;
    #pragma unroll
    for (int d = 1; d < 64; d <<= 1) {
        unsigned q = __shfl_up(p, d);
        if ((tl & 63) >= d) p += q;
    }
    if (threadIdx.x == 63) wtotS = p;
    __syncthreads();
    unsigned excl = base + ((tl >= 64) ? wtotS : 0u) + p - v;
    if (threadIdx.x < 128) {
        ncur[tl] = excl;
        if (tl < nodes) offs[b * BKT + tl] = excl;
    }
    if (b == NB - 1 && threadIdx.x == 0) offs[N] = end;
    __syncthreads();
    for (int i = threadIdx.x; i < cnt; i += 256) {
        unsigned r = recs[i];
        unsigned pos = atomicAdd(&ncur[r & (BKT - 1)], 1u);
        rbuf[pos] = r >> 7;
    }
}

// ---------------------------------------------------------------------------
// K5: layer-1 GAT aggregation. One wave per dst node, 8 lanes/edge
// (slot = lane>>3, head = lane&7), exp/lrelu once per (edge,head),
// 4 edges in flight per lane. Fused epilogue: relu(acc/den+b1) . W2 -> h2.
// ---------------------------------------------------------------------------
__global__ __launch_bounds__(256) void k_gat1(
    const unsigned* __restrict__ offs, const int* __restrict__ csr,
    const float4* __restrict__ h1q,
    const float* __restrict__ as1, const float* __restrict__ ad1,
    const float* __restrict__ b1, const float* __restrict__ W2,
    float* __restrict__ h2, int N)
{
    const int lane = threadIdx.x & 63;
    const int n = blockIdx.x * (blockDim.x >> 6) + (threadIdx.x >> 6);
    if (n >= N) return;
    const int slot = lane >> 3;
    const int head = lane & 7;
    const unsigned s0 = offs[n];
    const unsigned deg = offs[n + 1] - s0;
    const float ad = ad1[n * NHEAD + head];

    float acc[8] = {};
    float den = 0.f;

    unsigned k = (unsigned)slot;
    for (; k + 24 < deg; k += 32) {
        int sA = csr[s0 + k],      sB = csr[s0 + k + 8];
        int sC = csr[s0 + k + 16], sD = csr[s0 + k + 24];
        float aA = as1[sA * NHEAD + head], aB = as1[sB * NHEAD + head];
        float aC = as1[sC * NHEAD + head], aD = as1[sD * NHEAD + head];
        float4 rA = h1q[(unsigned)sA * 8u + head];
        float4 rB = h1q[(unsigned)sB * 8u + head];
        float4 rC = h1q[(unsigned)sC * 8u + head];
        float4 rD = h1q[(unsigned)sD * 8u + head];
        float pA = __expf(lrelu(aA + ad));
        float pB = __expf(lrelu(aB + ad));
        float pC = __expf(lrelu(aC + ad));
        float pD = __expf(lrelu(aD + ad));
        den += (pA + pB) + (pC + pD);
        const __half2* hA = (const __half2*)&rA;
        const __half2* hB = (const __half2*)&rB;
        const __half2* hC = (const __half2*)&rC;
        const __half2* hD = (const __half2*)&rD;
        #pragma unroll
        for (int j = 0; j < 4; ++j) {
            float2 fA = __half22float2(hA[j]);
            float2 fB = __half22float2(hB[j]);
            float2 fC = __half22float2(hC[j]);
            float2 fD = __half22float2(hD[j]);
            acc[2 * j]     = fmaf(pA, fA.x, acc[2 * j]);
            acc[2 * j + 1] = fmaf(pA, fA.y, acc[2 * j + 1]);
            acc[2 * j]     = fmaf(pB, fB.x, acc[2 * j]);
            acc[2 * j + 1] = fmaf(pB, fB.y, acc[2 * j + 1]);
            acc[2 * j]     = fmaf(pC, fC.x, acc[2 * j]);
            acc[2 * j + 1] = fmaf(pC, fC.y, acc[2 * j + 1]);
            acc[2 * j]     = fmaf(pD, fD.x, acc[2 * j]);
            acc[2 * j + 1] = fmaf(pD, fD.y, acc[2 * j + 1]);
        }
    }
    for (; k + 8 < deg; k += 16) {
        int sA = csr[s0 + k], sB = csr[s0 + k + 8];
        float aA = as1[sA * NHEAD + head], aB = as1[sB * NHEAD + head];
        float4 rA = h1q[(unsigned)sA * 8u + head];
        float4 rB = h1q[(unsigned)sB * 8u + head];
        float pA = __expf(lrelu(aA + ad));
        float pB = __expf(lrelu(aB + ad));
        den += pA + pB;
        const __half2* hA = (const __half2*)&rA;
        const __half2* hB = (const __half2*)&rB;
        #pragma unroll
        for (int j = 0; j < 4; ++j) {
            float2 fA = __half22float2(hA[j]);
            float2 fB = __half22float2(hB[j]);
            acc[2 * j]     = fmaf(pA, fA.x, acc[2 * j]);
            acc[2 * j + 1] = fmaf(pA, fA.y, acc[2 * j + 1]);
            acc[2 * j]     = fmaf(pB, fB.x, acc[2 * j]);
            acc[2 * j + 1] = fmaf(pB, fB.y, acc[2 * j + 1]);
        }
    }
    if (k < deg) {
        int s = csr[s0 + k];
        float a = as1[s * NHEAD + head];
        float4 r = h1q[(unsigned)s * 8u + head];
        float p = __expf(lrelu(a + ad));
        den += p;
        const __half2* hh = (const __half2*)&r;
        #pragma unroll
        for (int j = 0; j < 4; ++j) {
            float2 f = __half22float2(hh[j]);
            acc[2 * j]     = fmaf(p, f.x, acc[2 * j]);
            acc[2 * j + 1] = fmaf(p, f.y, acc[2 * j + 1]);
        }
    }

    #pragma unroll
    for (int r = 0; r < 8; ++r) {
        acc[r] += __shfl_xor(acc[r], 8);
        acc[r] += __shfl_xor(acc[r], 16);
        acc[r] += __shfl_xor(acc[r], 32);
    }
    den += __shfl_xor(den, 8);
    den += __shfl_xor(den, 16);
    den += __shfl_xor(den, 32);

    const float4 b0 = ((const float4*)b1)[head * 2];
    const float4 b1v = ((const float4*)b1)[head * 2 + 1];
    const float4 w0 = ((const float4*)W2)[head * 2];
    const float4 w1v = ((const float4*)W2)[head * 2 + 1];
    const float inv = 1.f / den;
    float tt = 0.f;
    tt += fmaxf(fmaf(acc[0], inv, b0.x), 0.f) * w0.x;
    tt += fmaxf(fmaf(acc[1], inv, b0.y), 0.f) * w0.y;
    tt += fmaxf(fmaf(acc[2], inv, b0.z), 0.f) * w0.z;
    tt += fmaxf(fmaf(acc[3], inv, b0.w), 0.f) * w0.w;
    tt += fmaxf(fmaf(acc[4], inv, b1v.x), 0.f) * w1v.x;
    tt += fmaxf(fmaf(acc[5], inv, b1v.y), 0.f) * w1v.y;
    tt += fmaxf(fmaf(acc[6], inv, b1v.z), 0.f) * w1v.z;
    tt += fmaxf(fmaf(acc[7], inv, b1v.w), 0.f) * w1v.w;
    tt += __shfl_xor(tt, 1);
    tt += __shfl_xor(tt, 2);
    tt += __shfl_xor(tt, 4);
    if (lane == 0) h2[n] = tt;
}

// ---------------------------------------------------------------------------
// K6 (fused): layer-2 GAT + mean-pool accumulate, 64 nodes/block,
// wave-0 segmented reduce, padded gacc atomics.
// ---------------------------------------------------------------------------
__global__ __launch_bounds__(1024) void k_gat2pool(
    const unsigned* __restrict__ offs, const int* __restrict__ csr,
    const float* __restrict__ h2, const int* __restrict__ batch,
    const float* __restrict__ a_src2, const float* __restrict__ a_dst2,
    const float* __restrict__ b2, float* __restrict__ gacc, int N)
{
    __shared__ float vals[64];
    __shared__ int gid[64];
    const int t = threadIdx.x;
    if (t < 64) gid[t] = -1;
    __syncthreads();

    const int lane = t & 63;
    const int ql = lane & 15;
    const int slot = (t >> 6) * 4 + (lane >> 4);
    const int n = blockIdx.x * 64 + slot;

    if (n < N) {
        const float aS = a_src2[0], aD = a_dst2[0];
        const unsigned s0 = offs[n], s1 = offs[n + 1];
        const float ad = h2[n] * aD;
        float num = 0.f, den = 0.f;
        for (unsigned j = s0 + (unsigned)ql; j < s1; j += 16) {
            float hs = h2[csr[j]];
            float p = __expf(lrelu(hs * aS + ad));
            num = fmaf(p, hs, num);
            den += p;
        }
        #pragma unroll
        for (int msk = 1; msk < 16; msk <<= 1) {
            num += __shfl_xor(num, msk);
            den += __shfl_xor(den, msk);
        }
        if (ql == 0) {
            vals[slot] = num / den + b2[0];
            gid[slot] = batch[n];
        }
    }
    __syncthreads();

    if (t < 64) {
        int g = gid[t];
        float o = (g >= 0) ? vals[t] : 0.f;
        const int g0 = __shfl(g, 0);
        const bool same = (g == g0);
        float s = same ? o : 0.f;
        float c = (same && g >= 0) ? 1.f : 0.f;
        #pragma unroll
        for (int msk = 1; msk < 64; msk <<= 1) {
            s += __shfl_xor(s, msk);
            c += __shfl_xor(c, msk);
        }
        if (t == 0) {
            unsafeAtomicAdd(&gacc[g0 * 16], s);
            unsafeAtomicAdd(&gacc[g0 * 16 + 1], c);
        }
        if (g >= 0 && !same) {
            unsafeAtomicAdd(&gacc[g * 16], o);
            unsafeAtomicAdd(&gacc[g * 16 + 1], 1.0f);
        }
    }
}

// ---------------------------------------------------------------------------
// K7: final per-graph mean
// ---------------------------------------------------------------------------
__global__ void k_final(const float* __restrict__ gacc,
                        float* __restrict__ out, int G)
{
    int g = blockIdx.x * blockDim.x + threadIdx.x;
    if (g < G) out[g] = gacc[g * 16] / fmaxf(gacc[g * 16 + 1], 1.0f);
}

// ---------------------------------------------------------------------------
extern "C" void kernel_launch(void* const* d_in, const int* in_sizes, int n_in,
                              void* d_out, int out_size, void* d_ws, size_t ws_size,
                              hipStream_t stream)
{
    const float* x      = (const float*)d_in[0];
    const int*   eidx   = (const int*)d_in[1];
    const int*   batch  = (const int*)d_in[2];
    const float* W1     = (const float*)d_in[3];
    const float* a_src1 = (const float*)d_in[4];
    const float* a_dst1 = (const float*)d_in[5];
    const float* b1     = (const float*)d_in[6];
    const float* W2     = (const float*)d_in[7];
    const float* a_src2 = (const float*)d_in[8];
    const float* a_dst2 = (const float*)d_in[9];
    const float* b2     = (const float*)d_in[10];

    const int N = in_sizes[0] / NF;      // 50000
    const int E = in_sizes[1] / 2;       // 1600000
    const int G = out_size;              // 64
    const int ETOT = E + N;
    const int NB = (N + BKT - 1) / BKT;  // 391 buckets
    const int CH = (ETOT + NBLK - 1) / NBLK;
    const int GB = (N + BM - 1) / BM;    // 391 gemm blocks

    // workspace layout (bytes)
    char* w = (char*)d_ws;
    __half*   h1h   = (__half*)(w + 0);           //  6,400,000 (fp16)
    float*    as1   = (float*)(w + 6400000);      //  1,600,000
    float*    ad1   = (float*)(w + 8000000);      //  1,600,000
    float*    h2    = (float*)(w + 9600000);      //    200,000
    unsigned* offs  = (unsigned*)(w + 9800000);   //    200,064
    unsigned* rbuf  = (unsigned*)(w + 10000064);  //  6,600,000 (records -> csr)
    unsigned* M     = (unsigned*)(w + 16600064);  //    400,384 (NB*NBLK)
    unsigned* Bbase = (unsigned*)(w + 17000448);  //      2,048
    float*    gacc  = (float*)(w + 17002496);     //      4,096 (64 graphs x 16)

    k_front<<<GB + NBLK, 256, 0, stream>>>(x, W1, a_src1, a_dst1,
                                           h1h, as1, ad1,
                                           eidx, M, gacc, N, E, GB, NB, CH);
    k_scan2<<<1, 1024, 0, stream>>>(M, Bbase, NB);
    k_bscatter<<<NBLK, 256, 0, stream>>>(eidx, E, N, NB, CH, M, rbuf);
    k_csr<<<NB, 256, 0, stream>>>(Bbase, N, NB, rbuf, offs);

    const int* csr = (const int*)rbuf;
    k_gat1<<<(N + 3) / 4, 256, 0, stream>>>(offs, csr, (const float4*)h1h,
                                            as1, ad1, b1, W2, h2, N);
    k_gat2pool<<<(N + 63) / 64, 1024, 0, stream>>>(offs, csr, h2, batch,
                                                   a_src2, a_dst2, b2, gacc, N);
    k_final<<<1, 64, 0, stream>>>(gacc, (float*)d_out, G);
}

// Round 13
// 132.480 us; speedup vs baseline: 3.9894x; 1.0923x over previous
//
#include <hip/hip_runtime.h>
#include <hip/hip_bf16.h>
#include <hip/hip_fp16.h>
#include <math.h>

#define NF 256    // input features
#define NO 64     // heads*c1 = 8*8
#define NHEAD 8
#define NEG_SLOPE 0.2f
#define BKT 128   // nodes per dst-bucket (d>>7); d_local = 7 bits
#define NBLK 256  // edge-chunk blocks for binning
#define RCAP 8192 // LDS record capacity in k_csr

__device__ __forceinline__ float lrelu(float x) { return x > 0.f ? x : NEG_SLOPE * x; }

typedef _Float16 f16x8 __attribute__((ext_vector_type(8)));
typedef float f32x4 __attribute__((ext_vector_type(4)));

__device__ __forceinline__ unsigned f2u(float a, float b) {
    __half2 h = __float22half2_rn(make_float2(a, b));
    return *(unsigned*)&h;
}

// ---------------------------------------------------------------------------
// K1 (fused): blocks [0,GB) = MFMA GEMM h1=x@W1 (fp16 in, f32 accum) + fused
// alphas + fp16 h1 store; blocks [GB,GB+NBLK) = bucket histogram -> M[b][blk].
// GEMM: 64x64 block, 4 waves; wave w = rows 16w..16w+15 as 4 MFMA col-tiles
// (mfma_f32_16x16x32_f16, K-loop 2 tiles x 4 steps). LDS 34.8KB: x rows and
// W TRANSPOSED (wl2[col][k]) as fp16-pair uints, row stride 68 (16B-aligned,
// <=2-way banks). Fragment layouts: A[m=l&15][k=(l>>4)*8+j],
// B[k=(l>>4)*8+j][n=l&15], D[m=(l>>4)*4+j][n=l&15] (m89-verified convention).
// f32-VALU GEMM variants all plateaued at ~41us (VALU-issue floor ~11us +
// un-hidden latency); fdot2 variants spilled. MFMA replaces the compute pipe.
// ---------------------------------------------------------------------------
__global__ __launch_bounds__(256) void k_front(
    const float* __restrict__ x, const float* __restrict__ W,
    const float* __restrict__ a_src, const float* __restrict__ a_dst,
    __half* __restrict__ h1h, float* __restrict__ as1, float* __restrict__ ad1,
    const int* __restrict__ eidx, unsigned* __restrict__ M,
    float* __restrict__ gacc, int N, int E, int GB, int NB, int CH)
{
    __shared__ unsigned xl2[64][68];   // [row][k-pair uint], 17408 B
    __shared__ unsigned wl2[64][68];   // [col][k-pair uint], 17408 B

    if (blockIdx.x >= GB) {
        // ---- histogram path (aliases xl2) ----
        unsigned* hist = &xl2[0][0];
        for (int i = threadIdx.x; i < NB; i += 256) hist[i] = 0;
        __syncthreads();
        const int blk = blockIdx.x - GB;
        const int lo = blk * CH;
        const int hi = min(lo + CH, E + N);
        for (int i = lo + (int)threadIdx.x; i < hi; i += 256) {
            int d = (i < E) ? eidx[E + i] : (i - E);
            atomicAdd(&hist[d >> 7], 1u);
        }
        __syncthreads();
        for (int b = threadIdx.x; b < NB; b += 256)
            M[(size_t)b * NBLK + blk] = hist[b];
        return;
    }

    // ---- GEMM path ----
    if (blockIdx.x == 0) {
        for (int i = threadIdx.x; i < 1024; i += 256) gacc[i] = 0.f;  // 64 x 16
    }
    const int t   = threadIdx.x;
    const int lw  = t & 63;        // lane
    const int wv  = t >> 6;        // wave 0..3 -> rows 16wv..16wv+15
    const int row0 = blockIdx.x * 64;

    f32x4 acc[4] = {};             // 4 col-tiles x 4 f32

    for (int kc = 0; kc < NF; kc += 128) {
        if (kc) __syncthreads();
        // stage x tile: 64 rows x 128 k. thread: row t>>2, k-quarter t&3.
        {
            const int r = t >> 2, q = t & 3;
            int row = row0 + r; if (row >= N) row = N - 1;
            const float4* xs = (const float4*)(x + (size_t)row * NF + kc + q * 32);
            #pragma unroll
            for (int i = 0; i < 8; ++i) {
                float4 v = xs[i];
                xl2[r][q * 16 + 2 * i]     = f2u(v.x, v.y);
                xl2[r][q * 16 + 2 * i + 1] = f2u(v.z, v.w);
            }
        }
        // stage W tile TRANSPOSED: thread: col t&63, k-segment t>>6 (32 k's).
        {
            const int c = t & 63, seg = t >> 6;
            #pragma unroll
            for (int m = 0; m < 16; ++m) {
                int k = kc + seg * 32 + 2 * m;
                float w0 = W[(size_t)k * NO + c];
                float w1 = W[(size_t)(k + 1) * NO + c];
                wl2[c][seg * 16 + m] = f2u(w0, w1);
            }
        }
        __syncthreads();

        const int mrow = 16 * wv + (lw & 15);
        const int fcol = (lw >> 4) * 4;       // uint offset of this lane's 8 k's
        #pragma unroll
        for (int ks = 0; ks < 4; ++ks) {
            f16x8 a = *(const f16x8*)&xl2[mrow][ks * 16 + fcol];
            #pragma unroll
            for (int ct = 0; ct < 4; ++ct) {
                f16x8 b = *(const f16x8*)&wl2[16 * ct + (lw & 15)][ks * 16 + fcol];
                acc[ct] = __builtin_amdgcn_mfma_f32_16x16x32_f16(a, b, acc[ct], 0, 0, 0);
            }
        }
    }

    // epilogue: D[m=(lw>>4)*4+j][n=lw&15]; store h1 fp16 + per-head alphas
    const int colb = lw & 15;
    #pragma unroll
    for (int ct = 0; ct < 4; ++ct) {
        const int col = 16 * ct + colb;
        const float asc = a_src[col];
        const float adc = a_dst[col];
        #pragma unroll
        for (int j = 0; j < 4; ++j) {
            const int rowAbs = row0 + 16 * wv + (lw >> 4) * 4 + j;
            float v = acc[ct][j];
            float vs = v * asc, vd = v * adc;
            vs += __shfl_xor(vs, 1); vs += __shfl_xor(vs, 2); vs += __shfl_xor(vs, 4);
            vd += __shfl_xor(vd, 1); vd += __shfl_xor(vd, 2); vd += __shfl_xor(vd, 4);
            if (rowAbs < N) {
                h1h[(size_t)rowAbs * NO + col] = __float2half(v);
                if ((colb & 7) == 0) {
                    int head = 2 * ct + (colb >> 3);
                    as1[rowAbs * NHEAD + head] = vs;
                    ad1[rowAbs * NHEAD + head] = vd;
                }
            }
        }
    }
}

// ---------------------------------------------------------------------------
// K2: single block, 1024 threads. Row-sum M -> totals; serial scan -> Bbase;
// per-row uint4 wave scans -> in-place scatter cursors in M.
// ---------------------------------------------------------------------------
__global__ __launch_bounds__(1024) void k_scan2(
    unsigned* __restrict__ M, unsigned* __restrict__ Bbase, int NB)
{
    __shared__ unsigned tot[512];
    __shared__ unsigned basel[513];
    const int t = threadIdx.x, lane = t & 63, w = t >> 6;  // 16 waves

    for (int b = w; b < NB; b += 16) {
        uint4 v = ((const uint4*)&M[(size_t)b * NBLK])[lane];
        unsigned s = v.x + v.y + v.z + v.w;
        #pragma unroll
        for (int m = 1; m < 64; m <<= 1) s += __shfl_xor(s, m);
        if (lane == 0) tot[b] = s;
    }
    __syncthreads();
    if (t == 0) {
        unsigned r = 0;
        for (int b = 0; b < NB; ++b) { basel[b] = r; r += tot[b]; }
        basel[NB] = r;
    }
    __syncthreads();
    for (int b = t; b <= NB; b += 1024) Bbase[b] = basel[b];
    for (int b = w; b < NB; b += 16) {
        uint4 v = ((const uint4*)&M[(size_t)b * NBLK])[lane];
        unsigned lsum = v.x + v.y + v.z + v.w;
        unsigned p = lsum;
        #pragma unroll
        for (int d = 1; d < 64; d <<= 1) {
            unsigned q = __shfl_up(p, d);
            if (lane >= d) p += q;
        }
        unsigned c0 = basel[b] + p - lsum;
        uint4 o;
        o.x = c0;
        o.y = c0 + v.x;
        o.z = o.y + v.y;
        o.w = o.z + v.z;
        ((uint4*)&M[(size_t)b * NBLK])[lane] = o;
    }
}

// ---------------------------------------------------------------------------
// K3: scatter packed records (s<<7 | d_local) into bucket-contiguous regions.
// ---------------------------------------------------------------------------
__global__ __launch_bounds__(256) void k_bscatter(
    const int* __restrict__ eidx, int E, int N, int NB, int CH,
    const unsigned* __restrict__ M, unsigned* __restrict__ rbuf)
{
    __shared__ unsigned cur[512];
    const int blk = blockIdx.x;
    for (int b = threadIdx.x; b < NB; b += 256)
        cur[b] = M[(size_t)b * NBLK + blk];
    __syncthreads();
    const int lo = blk * CH;
    const int hi = min(lo + CH, E + N);
    for (int i = lo + (int)threadIdx.x; i < hi; i += 256) {
        int s, d;
        if (i < E) { s = eidx[i]; d = eidx[E + i]; }
        else       { s = i - E;   d = i - E; }
        unsigned pos = atomicAdd(&cur[d >> 7], 1u);
        rbuf[pos] = ((unsigned)s << 7) | (unsigned)(d & (BKT - 1));
    }
}

// ---------------------------------------------------------------------------
// K4: per-bucket LDS counting sort -> node-ordered csr (in place) + offs.
// ---------------------------------------------------------------------------
__global__ __launch_bounds__(256) void k_csr(
    const unsigned* __restrict__ Bbase, int N, int NB,
    unsigned* __restrict__ rbuf, unsigned* __restrict__ offs)
{
    __shared__ unsigned recs[RCAP];
    __shared__ unsigned nhist[BKT];
    __shared__ unsigned ncur[BKT];
    __shared__ unsigned wtotS;
    const int b = blockIdx.x;
    const unsigned base = Bbase[b], end = Bbase[b + 1];
    const int cnt = (int)(end - base);
    const int nodes = min(BKT, N - b * BKT);

    for (int i = threadIdx.x; i < BKT; i += 256) nhist[i] = 0;
    __syncthreads();
    for (int i = threadIdx.x; i < cnt; i += 256) {
        unsigned r = rbuf[base + i];
        recs[i] = r;
        atomicAdd(&nhist[r & (BKT - 1)], 1u);
    }
    __syncthreads();
    const int tl = threadIdx.x & 127;
    unsigned v = nhist[tl], p = v;
    #pragma unroll
    for (int d = 1; d < 64; d <<= 1) {
        unsigned q = __shfl_up(p, d);
        if ((tl & 63) >= d) p += q;
    }
    if (threadIdx.x == 63) wtotS = p;
    __syncthreads();
    unsigned excl = base + ((tl >= 64) ? wtotS : 0u) + p - v;
    if (threadIdx.x < 128) {
        ncur[tl] = excl;
        if (tl < nodes) offs[b * BKT + tl] = excl;
    }
    if (b == NB - 1 && threadIdx.x == 0) offs[N] = end;
    __syncthreads();
    for (int i = threadIdx.x; i < cnt; i += 256) {
        unsigned r = recs[i];
        unsigned pos = atomicAdd(&ncur[r & (BKT - 1)], 1u);
        rbuf[pos] = r >> 7;
    }
}

// ---------------------------------------------------------------------------
// K5: layer-1 GAT aggregation. One wave per dst node, 8 lanes/edge
// (slot = lane>>3, head = lane&7), exp/lrelu once per (edge,head),
// 4 edges in flight per lane. Fused epilogue: relu(acc/den+b1) . W2 -> h2.
// ---------------------------------------------------------------------------
__global__ __launch_bounds__(256) void k_gat1(
    const unsigned* __restrict__ offs, const int* __restrict__ csr,
    const float4* __restrict__ h1q,
    const float* __restrict__ as1, const float* __restrict__ ad1,
    const float* __restrict__ b1, const float* __restrict__ W2,
    float* __restrict__ h2, int N)
{
    const int lane = threadIdx.x & 63;
    const int n = blockIdx.x * (blockDim.x >> 6) + (threadIdx.x >> 6);
    if (n >= N) return;
    const int slot = lane >> 3;
    const int head = lane & 7;
    const unsigned s0 = offs[n];
    const unsigned deg = offs[n + 1] - s0;
    const float ad = ad1[n * NHEAD + head];

    float acc[8] = {};
    float den = 0.f;

    unsigned k = (unsigned)slot;
    for (; k + 24 < deg; k += 32) {
        int sA = csr[s0 + k],      sB = csr[s0 + k + 8];
        int sC = csr[s0 + k + 16], sD = csr[s0 + k + 24];
        float aA = as1[sA * NHEAD + head], aB = as1[sB * NHEAD + head];
        float aC = as1[sC * NHEAD + head], aD = as1[sD * NHEAD + head];
        float4 rA = h1q[(unsigned)sA * 8u + head];
        float4 rB = h1q[(unsigned)sB * 8u + head];
        float4 rC = h1q[(unsigned)sC * 8u + head];
        float4 rD = h1q[(unsigned)sD * 8u + head];
        float pA = __expf(lrelu(aA + ad));
        float pB = __expf(lrelu(aB + ad));
        float pC = __expf(lrelu(aC + ad));
        float pD = __expf(lrelu(aD + ad));
        den += (pA + pB) + (pC + pD);
        const __half2* hA = (const __half2*)&rA;
        const __half2* hB = (const __half2*)&rB;
        const __half2* hC = (const __half2*)&rC;
        const __half2* hD = (const __half2*)&rD;
        #pragma unroll
        for (int j = 0; j < 4; ++j) {
            float2 fA = __half22float2(hA[j]);
            float2 fB = __half22float2(hB[j]);
            float2 fC = __half22float2(hC[j]);
            float2 fD = __half22float2(hD[j]);
            acc[2 * j]     = fmaf(pA, fA.x, acc[2 * j]);
            acc[2 * j + 1] = fmaf(pA, fA.y, acc[2 * j + 1]);
            acc[2 * j]     = fmaf(pB, fB.x, acc[2 * j]);
            acc[2 * j + 1] = fmaf(pB, fB.y, acc[2 * j + 1]);
            acc[2 * j]     = fmaf(pC, fC.x, acc[2 * j]);
            acc[2 * j + 1] = fmaf(pC, fC.y, acc[2 * j + 1]);
            acc[2 * j]     = fmaf(pD, fD.x, acc[2 * j]);
            acc[2 * j + 1] = fmaf(pD, fD.y, acc[2 * j + 1]);
        }
    }
    for (; k + 8 < deg; k += 16) {
        int sA = csr[s0 + k], sB = csr[s0 + k + 8];
        float aA = as1[sA * NHEAD + head], aB = as1[sB * NHEAD + head];
        float4 rA = h1q[(unsigned)sA * 8u + head];
        float4 rB = h1q[(unsigned)sB * 8u + head];
        float pA = __expf(lrelu(aA + ad));
        float pB = __expf(lrelu(aB + ad));
        den += pA + pB;
        const __half2* hA = (const __half2*)&rA;
        const __half2* hB = (const __half2*)&rB;
        #pragma unroll
        for (int j = 0; j < 4; ++j) {
            float2 fA = __half22float2(hA[j]);
            float2 fB = __half22float2(hB[j]);
            acc[2 * j]     = fmaf(pA, fA.x, acc[2 * j]);
            acc[2 * j + 1] = fmaf(pA, fA.y, acc[2 * j + 1]);
            acc[2 * j]     = fmaf(pB, fB.x, acc[2 * j]);
            acc[2 * j + 1] = fmaf(pB, fB.y, acc[2 * j + 1]);
        }
    }
    if (k < deg) {
        int s = csr[s0 + k];
        float a = as1[s * NHEAD + head];
        float4 r = h1q[(unsigned)s * 8u + head];
        float p = __expf(lrelu(a + ad));
        den += p;
        const __half2* hh = (const __half2*)&r;
        #pragma unroll
        for (int j = 0; j < 4; ++j) {
            float2 f = __half22float2(hh[j]);
            acc[2 * j]     = fmaf(p, f.x, acc[2 * j]);
            acc[2 * j + 1] = fmaf(p, f.y, acc[2 * j + 1]);
        }
    }

    #pragma unroll
    for (int r = 0; r < 8; ++r) {
        acc[r] += __shfl_xor(acc[r], 8);
        acc[r] += __shfl_xor(acc[r], 16);
        acc[r] += __shfl_xor(acc[r], 32);
    }
    den += __shfl_xor(den, 8);
    den += __shfl_xor(den, 16);
    den += __shfl_xor(den, 32);

    const float4 b0 = ((const float4*)b1)[head * 2];
    const float4 b1v = ((const float4*)b1)[head * 2 + 1];
    const float4 w0 = ((const float4*)W2)[head * 2];
    const float4 w1v = ((const float4*)W2)[head * 2 + 1];
    const float inv = 1.f / den;
    float tt = 0.f;
    tt += fmaxf(fmaf(acc[0], inv, b0.x), 0.f) * w0.x;
    tt += fmaxf(fmaf(acc[1], inv, b0.y), 0.f) * w0.y;
    tt += fmaxf(fmaf(acc[2], inv, b0.z), 0.f) * w0.z;
    tt += fmaxf(fmaf(acc[3], inv, b0.w), 0.f) * w0.w;
    tt += fmaxf(fmaf(acc[4], inv, b1v.x), 0.f) * w1v.x;
    tt += fmaxf(fmaf(acc[5], inv, b1v.y), 0.f) * w1v.y;
    tt += fmaxf(fmaf(acc[6], inv, b1v.z), 0.f) * w1v.z;
    tt += fmaxf(fmaf(acc[7], inv, b1v.w), 0.f) * w1v.w;
    tt += __shfl_xor(tt, 1);
    tt += __shfl_xor(tt, 2);
    tt += __shfl_xor(tt, 4);
    if (lane == 0) h2[n] = tt;
}

// ---------------------------------------------------------------------------
// K6 (fused): layer-2 GAT + mean-pool accumulate, 64 nodes/block,
// wave-0 segmented reduce, padded gacc atomics.
// ---------------------------------------------------------------------------
__global__ __launch_bounds__(1024) void k_gat2pool(
    const unsigned* __restrict__ offs, const int* __restrict__ csr,
    const float* __restrict__ h2, const int* __restrict__ batch,
    const float* __restrict__ a_src2, const float* __restrict__ a_dst2,
    const float* __restrict__ b2, float* __restrict__ gacc, int N)
{
    __shared__ float vals[64];
    __shared__ int gid[64];
    const int t = threadIdx.x;
    if (t < 64) gid[t] = -1;
    __syncthreads();

    const int lane = t & 63;
    const int ql = lane & 15;
    const int slot = (t >> 6) * 4 + (lane >> 4);
    const int n = blockIdx.x * 64 + slot;

    if (n < N) {
        const float aS = a_src2[0], aD = a_dst2[0];
        const unsigned s0 = offs[n], s1 = offs[n + 1];
        const float ad = h2[n] * aD;
        float num = 0.f, den = 0.f;
        for (unsigned j = s0 + (unsigned)ql; j < s1; j += 16) {
            float hs = h2[csr[j]];
            float p = __expf(lrelu(hs * aS + ad));
            num = fmaf(p, hs, num);
            den += p;
        }
        #pragma unroll
        for (int msk = 1; msk < 16; msk <<= 1) {
            num += __shfl_xor(num, msk);
            den += __shfl_xor(den, msk);
        }
        if (ql == 0) {
            vals[slot] = num / den + b2[0];
            gid[slot] = batch[n];
        }
    }
    __syncthreads();

    if (t < 64) {
        int g = gid[t];
        float o = (g >= 0) ? vals[t] : 0.f;
        const int g0 = __shfl(g, 0);
        const bool same = (g == g0);
        float s = same ? o : 0.f;
        float c = (same && g >= 0) ? 1.f : 0.f;
        #pragma unroll
        for (int msk = 1; msk < 64; msk <<= 1) {
            s += __shfl_xor(s, msk);
            c += __shfl_xor(c, msk);
        }
        if (t == 0) {
            unsafeAtomicAdd(&gacc[g0 * 16], s);
            unsafeAtomicAdd(&gacc[g0 * 16 + 1], c);
        }
        if (g >= 0 && !same) {
            unsafeAtomicAdd(&gacc[g * 16], o);
            unsafeAtomicAdd(&gacc[g * 16 + 1], 1.0f);
        }
    }
}

// ---------------------------------------------------------------------------
// K7: final per-graph mean
// ---------------------------------------------------------------------------
__global__ void k_final(const float* __restrict__ gacc,
                        float* __restrict__ out, int G)
{
    int g = blockIdx.x * blockDim.x + threadIdx.x;
    if (g < G) out[g] = gacc[g * 16] / fmaxf(gacc[g * 16 + 1], 1.0f);
}

// ---------------------------------------------------------------------------
extern "C" void kernel_launch(void* const* d_in, const int* in_sizes, int n_in,
                              void* d_out, int out_size, void* d_ws, size_t ws_size,
                              hipStream_t stream)
{
    const float* x      = (const float*)d_in[0];
    const int*   eidx   = (const int*)d_in[1];
    const int*   batch  = (const int*)d_in[2];
    const float* W1     = (const float*)d_in[3];
    const float* a_src1 = (const float*)d_in[4];
    const float* a_dst1 = (const float*)d_in[5];
    const float* b1     = (const float*)d_in[6];
    const float* W2     = (const float*)d_in[7];
    const float* a_src2 = (const float*)d_in[8];
    const float* a_dst2 = (const float*)d_in[9];
    const float* b2     = (const float*)d_in[10];

    const int N = in_sizes[0] / NF;      // 50000
    const int E = in_sizes[1] / 2;       // 1600000
    const int G = out_size;              // 64
    const int ETOT = E + N;
    const int NB = (N + BKT - 1) / BKT;  // 391 buckets
    const int CH = (ETOT + NBLK - 1) / NBLK;
    const int GB = (N + 63) / 64;        // 782 gemm blocks

    // workspace layout (bytes)
    char* w = (char*)d_ws;
    __half*   h1h   = (__half*)(w + 0);           //  6,400,000 (fp16)
    float*    as1   = (float*)(w + 6400000);      //  1,600,000
    float*    ad1   = (float*)(w + 8000000);      //  1,600,000
    float*    h2    = (float*)(w + 9600000);      //    200,000
    unsigned* offs  = (unsigned*)(w + 9800000);   //    200,064
    unsigned* rbuf  = (unsigned*)(w + 10000064);  //  6,600,000 (records -> csr)
    unsigned* M     = (unsigned*)(w + 16600064);  //    400,384 (NB*NBLK)
    unsigned* Bbase = (unsigned*)(w + 17000448);  //      2,048
    float*    gacc  = (float*)(w + 17002496);     //      4,096 (64 graphs x 16)

    k_front<<<GB + NBLK, 256, 0, stream>>>(x, W1, a_src1, a_dst1,
                                           h1h, as1, ad1,
                                           eidx, M, gacc, N, E, GB, NB, CH);
    k_scan2<<<1, 1024, 0, stream>>>(M, Bbase, NB);
    k_bscatter<<<NBLK, 256, 0, stream>>>(eidx, E, N, NB, CH, M, rbuf);
    k_csr<<<NB, 256, 0, stream>>>(Bbase, N, NB, rbuf, offs);

    const int* csr = (const int*)rbuf;
    k_gat1<<<(N + 3) / 4, 256, 0, stream>>>(offs, csr, (const float4*)h1h,
                                            as1, ad1, b1, W2, h2, N);
    k_gat2pool<<<(N + 63) / 64, 1024, 0, stream>>>(offs, csr, h2, batch,
                                                   a_src2, a_dst2, b2, gacc, N);
    k_final<<<1, 64, 0, stream>>>(gacc, (float*)d_out, G);
}